// Round 10
// baseline (1208.452 us; speedup 1.0000x reference)
//
#include <hip/hip_runtime.h>

#define DT 0.1f

typedef float v2f __attribute__((ext_vector_type(2)));

// Pack per-hidden-unit weights into one float4: (W1[0][j], W1[1][j], b1[j], W2[j])
__global__ void pack_weights(const float* __restrict__ W1, const float* __restrict__ b1,
                             const float* __restrict__ W2, float4* __restrict__ ws, int hidden) {
    int j = blockIdx.x * blockDim.x + threadIdx.x;
    if (j < hidden) {
        ws[j] = make_float4(W1[j], W1[hidden + j], b1[j], W2[j]);
    }
}

// Guaranteed packed fp32 FMA (VOP3P; operands are 64-bit VGPR pairs).
__device__ __forceinline__ v2f pk_fma(v2f a, v2f b, v2f c) {
    v2f d;
    asm("v_pk_fma_f32 %0, %1, %2, %3" : "=v"(d) : "v"(a), "v"(b), "v"(c));
    return d;
}

// DPP-based add-reduce (VALU pipe). 0xB1=xor1, 0x4E=xor2, 0x141=half-mirror (8-lane fold).
template <int CTRL>
__device__ __forceinline__ float dpp_add(float x) {
    int v = __builtin_amdgcn_mov_dpp(__float_as_int(x), CTRL, 0xf, 0xf, true);
    return x + __int_as_float(v);
}

// p = tid&7 owns hidden units [p*32, (p+1)*32); each 8-lane group carries FOUR
// consecutive elements e0..e0+3. Weights (128 regs) are AGPR-parked (rounds 3-7:
// unavoidable). Round 9's flaw: the per-q copy out of AGPR was rematerialized at
// EVERY use (512 accvgpr_reads/step, ~845 inst/wave-step measured). Fix: pin the
// per-q copies with an asm (non-duplicable) so exactly 128 copy-dwords/step are
// issued and each weight is then used 4x from a VGPR.
__global__ __launch_bounds__(256, 2) void waterbalance(
    const float* __restrict__ inflows, const float* __restrict__ storage0,
    const float4* __restrict__ ws, const float* __restrict__ b2,
    float* __restrict__ out_storages, float* __restrict__ out_outflows,
    int iters, int batch)
{
    const int tid = blockIdx.x * blockDim.x + threadIdx.x;
    const int g = tid >> 3;          // element-quad id
    const int p = tid & 7;           // unit-block within element
    const int nquad = batch >> 2;
    if (g >= nquad) return;
    const int e0 = g << 2;           // four consecutive elements

    // This lane's 32 units' weights as v2f pairs: 64 v2f = 128 regs (AGPR-parked).
    v2f wx[16], wy[16], wb[16], w2[16];
    #pragma unroll
    for (int q = 0; q < 16; ++q) {
        float4 a = ws[p * 32 + 2 * q];
        float4 b = ws[p * 32 + 2 * q + 1];
        wx[q] = (v2f){a.x, b.x};
        wy[q] = (v2f){a.y, b.y};
        wb[q] = (v2f){a.z, b.z};
        w2[q] = (v2f){a.w, b.w};
    }
    // One-time opaque pin: prevents re-load-from-memory sinking (round 2 tell).
    #pragma unroll
    for (int q = 0; q < 16; ++q) {
        asm("" : "+v"(wx[q]), "+v"(wy[q]), "+v"(wb[q]), "+v"(w2[q]));
    }

    const float b2v = b2[0];

    float s[4], cur[4];
    #pragma unroll
    for (int r = 0; r < 4; ++r) s[r] = storage0[e0 + r];
    if (p == 0) {
        #pragma unroll
        for (int r = 0; r < 4; ++r) out_storages[e0 + r] = s[r];
    }
    #pragma unroll
    for (int r = 0; r < 4; ++r) cur[r] = inflows[e0 + r];

    for (int t = 0; t < iters; ++t) {
        // Prefetch next step's inflows (4 loads in flight over ~900cy compute).
        float nxt[4];
        if (t + 1 < iters) {
            const size_t bn = (size_t)(t + 1) * batch + e0;
            #pragma unroll
            for (int r = 0; r < 4; ++r) nxt[r] = inflows[bn + r];
        } else {
            #pragma unroll
            for (int r = 0; r < 4; ++r) nxt[r] = 0.0f;
        }

        const v2f zero2 = (v2f)(0.0f);
        v2f in2[4], s2[4], acc[4];
        #pragma unroll
        for (int r = 0; r < 4; ++r) {
            in2[r] = (v2f){cur[r], cur[r]};
            s2[r]  = (v2f){s[r], s[r]};
            acc[r] = zero2;
        }

        // q outer, r inner: each weight v2f copied out of its AGPR home ONCE
        // (the asm below cannot be rematerialized), then used for 4 elements.
        #pragma unroll
        for (int q = 0; q < 16; ++q) {
            v2f x = wx[q], y = wy[q], bb = wb[q], w = w2[q];
            asm("" : "+v"(x), "+v"(y), "+v"(bb), "+v"(w));
            #pragma unroll
            for (int r = 0; r < 4; ++r) {
                v2f z = pk_fma(in2[r], x, pk_fma(s2[r], y, bb));
                z = __builtin_elementwise_max(z, zero2);
                acc[r] = pk_fma(z, w, acc[r]);
            }
        }

        float of[4];
        #pragma unroll
        for (int r = 0; r < 4; ++r) {
            float part = acc[r].x + acc[r].y;
            part = dpp_add<0xB1>(part);    // xor 1
            part = dpp_add<0x4E>(part);    // xor 2
            part = dpp_add<0x141>(part);   // fold the two quads of the 8-group
            of[r] = part + b2v;
            s[r] = fmaf(DT, cur[r] - of[r], s[r]);   // identical across the 8 lanes
        }

        if (p == 0) {
            const size_t ot = (size_t)t * batch + e0;
            const size_t st = (size_t)(t + 1) * batch + e0;
            #pragma unroll
            for (int r = 0; r < 4; ++r) {
                out_outflows[ot + r] = of[r];
                out_storages[st + r] = s[r];
            }
        }

        #pragma unroll
        for (int r = 0; r < 4; ++r) cur[r] = nxt[r];
    }
}

extern "C" void kernel_launch(void* const* d_in, const int* in_sizes, int n_in,
                              void* d_out, int out_size, void* d_ws, size_t ws_size,
                              hipStream_t stream) {
    const float* inflows  = (const float*)d_in[0];
    const float* storage0 = (const float*)d_in[1];
    const float* W1       = (const float*)d_in[2];
    const float* b1       = (const float*)d_in[3];
    const float* W2       = (const float*)d_in[4];
    const float* b2       = (const float*)d_in[5];

    int batch  = in_sizes[1];                 // 65536
    int iters  = in_sizes[0] / batch;         // 512
    int hidden = in_sizes[3];                 // 256

    float4* ws = (float4*)d_ws;
    pack_weights<<<(hidden + 255) / 256, 256, 0, stream>>>(W1, b1, W2, ws, hidden);

    float* out_storages = (float*)d_out;                                // (iters+1, batch)
    float* out_outflows = out_storages + (size_t)(iters + 1) * batch;   // (iters, batch)

    int threads = (batch / 4) * 8;            // 131072
    waterbalance<<<(threads + 255) / 256, 256, 0, stream>>>(
        inflows, storage0, ws, b2, out_storages, out_outflows, iters, batch);
}